// Round 1
// baseline (242.908 us; speedup 1.0000x reference)
//
#include <hip/hip_runtime.h>
#include <math.h>

#define NUM_NODES 2000000
#define NUM_FLOPS 800000
#define NBX 168
#define NBY 480
#define NCK 8
#define NCE 8
#define NBINS (NBX * NBY)          // 80,640
#define YB_ROWS 30                 // y-bucket / tile granularity
#define NYB 16                     // y-buckets per column
#define NBUCK (NYB * NBX)          // 2,688 buckets; id = yb*NBX + col (cols contiguous!)
#define CAPB 608                   // worst bucket (col 167 + halo) ~431 expected; +41% margin
#define W 4                        // columns owned per ff_main block (tile = 30 rows x 4 cols)
#define KSTRIDE 68                 // ke-dim stride (64 + 4 pad) -> 8-way bank spread on reduce
#define S_INVSQRT2 0.7071067811865476f
#define FILL_THREADS (784 * 1024)  // >= NUM_FLOPS

// -------- workspace layout --------
// scale : float [NBINS]               @ float-offset 0          (322.6 KB)
// cnt   : int   [NBUCK]               @ float-offset NBINS      (10.8 KB)
// rec   : Rec12 [NBUCK * CAPB]        @ byte 333,312            (19.6 MB)
// total 19.96 MB (< 20.97 MB proven in R1)

struct Rec12 { float cx, cy; int keby; };   // keby = (by0 << 6) | ke

// Branch-free erf, Abramowitz-Stegun 7.1.26 (max abs err 1.5e-7).
__device__ __forceinline__ float fast_erf(float x) {
    float ax = fabsf(x);
    float t = __builtin_amdgcn_rcpf(fmaf(0.3275911f, ax, 1.0f));
    float p = t * fmaf(t, fmaf(t, fmaf(t, fmaf(t, 1.061405429f, -1.453152027f),
                                       1.421413741f), -0.284496736f), 0.254829592f);
    float r = fmaf(-p, __expf(-ax * ax), 1.0f);
    return copysignf(r, x);
}

__global__ void __launch_bounds__(1024)
ff_fill(const float* __restrict__ pos,
        const float* __restrict__ nsx,
        const float* __restrict__ nsy,
        const int* __restrict__ fi,
        const int* __restrict__ cs,
        int* __restrict__ cnt,
        Rec12* __restrict__ rec,
        float* __restrict__ out) {
    __shared__ int h[NBUCK];
    __shared__ int base[NBUCK];
    int tid = threadIdx.x;
    int f = blockIdx.x * blockDim.x + tid;

    // fused: zero the output array (replaces a memset dispatch)
    for (int g = f; g < NUM_NODES; g += FILL_THREADS) out[g] = 0.f;

    for (int j = tid; j < NBUCK; j += 1024) h[j] = 0;
    __syncthreads();

    bool valid = (f < NUM_FLOPS);
    int b1 = 0, b2 = -1, r1 = 0, r2 = 0, keby = 0;
    float cx = 0.f, cy = 0.f;
    if (valid) {
        int i = fi[f];
        cx = pos[i] + 0.5f * nsx[i];
        cy = pos[NUM_NODES + i] + 0.5f * nsy[i];
        int bx0 = (int)floorf(cx); bx0 = bx0 < 0 ? 0 : (bx0 > NBX - 1 ? NBX - 1 : bx0);
        int by0 = (int)floorf(cy); by0 = by0 < 0 ? 0 : (by0 > NBY - 1 ? NBY - 1 : by0);
        keby = (by0 << 6) | (cs[2 * f] * NCE + cs[2 * f + 1]);
        int yb = by0 / YB_ROWS;
        int rlo = by0 - yb * YB_ROWS;
        b1 = yb * NBX + bx0;
        r1 = atomicAdd(&h[b1], 1);
        if (rlo <= 1 && yb > 0)            b2 = b1 - NBX;   // halo up
        else if (rlo >= 28 && yb < NYB - 1) b2 = b1 + NBX;  // halo down
        if (b2 >= 0) r2 = atomicAdd(&h[b2], 1);
    }
    __syncthreads();
    for (int j = tid; j < NBUCK; j += 1024)
        base[j] = h[j] ? atomicAdd(&cnt[j], h[j]) : 0;   // one global atomic per (block,bucket)
    __syncthreads();
    if (valid) {
        Rec12 v; v.cx = cx; v.cy = cy; v.keby = keby;
        int s1 = base[b1] + r1;
        if (s1 < CAPB) rec[(size_t)b1 * CAPB + s1] = v;
        if (b2 >= 0) {
            int s2 = base[b2] + r2;
            if (s2 < CAPB) rec[(size_t)b2 * CAPB + s2] = v;
        }
    }
}

// Block owns a 30-row x W-column x 64-ke LDS tile. It reads the W+4 contiguous
// buckets whose records can touch its columns; each record is visited by only
// (W+4)/W = 2 blocks (was 5 when W=1). One visit serves up to W output columns
// with W+1 shared x-edge erfs and 6 INDEPENDENT y-edge erfs (no serial e_prev
// chain). start[] is fully unrolled/constant-indexed -> registers, and the next
// record is prefetched while the current one is processed.
__global__ void __launch_bounds__(512)
ff_main(const int* __restrict__ cnt,
        const Rec12* __restrict__ rec,
        float* __restrict__ scale) {
    __shared__ __align__(16) float acc[YB_ROWS * W * KSTRIDE];   // 8,160 f = 32,640 B
    int tid = threadIdx.x;
    int c0 = blockIdx.x * W;
    int yb = blockIdx.y;
    int y0 = yb * YB_ROWS;

    for (int j = tid; j < YB_ROWS * W * KSTRIDE; j += 512) acc[j] = 0.f;
    __syncthreads();

    // merged dense iteration over the (<= W+4) contiguous buckets
    int c_lo = c0 - 2 < 0 ? 0 : c0 - 2;
    int c_hi = c0 + W + 1 > NBX - 1 ? NBX - 1 : c0 + W + 1;
    int nb = c_hi - c_lo + 1;                  // 6..8
    int start[9];
    start[0] = 0;
#pragma unroll
    for (int k = 0; k < 8; ++k) {              // fully unrolled -> register-resident
        int n = 0;
        if (k < nb) { n = cnt[yb * NBX + c_lo + k]; n = n < CAPB ? n : CAPB; }
        start[k + 1] = start[k] + n;
    }
    int tot = start[8];
    const Rec12* bb = rec + (size_t)(yb * NBX + c_lo) * CAPB;

    int idx = tid;
    Rec12 v = {}; int kc = 0;
    if (idx < tot) {
        int k = 0, off = idx;
#pragma unroll
        for (int t = 1; t < 8; ++t) { bool g = idx >= start[t]; k = g ? t : k; off = g ? idx - start[t] : off; }
        v = bb[(size_t)k * CAPB + off];
        kc = k;
    }
    while (idx < tot) {
        // ---- prefetch next record (overlaps with compute below) ----
        int nidx = idx + 512;
        Rec12 vn = {}; int kn = 0;
        if (nidx < tot) {
            int k = 0, off = nidx;
#pragma unroll
            for (int t = 1; t < 8; ++t) { bool g = nidx >= start[t]; k = g ? t : k; off = g ? nidx - start[t] : off; }
            vn = bb[(size_t)k * CAPB + off];
            kn = k;
        }
        // ---- process current record ----
        float cx = v.cx, cy = v.cy;
        int ke  = v.keby & 63;
        int by0 = v.keby >> 6;
        int bx0 = c_lo + kc;                   // bucket column == record's bx0 (free!)
        float ex[W + 1], ey[6];
#pragma unroll
        for (int i = 0; i <= W; ++i)           // W+1 independent erfs (owned-column edges)
            ex[i] = fast_erf(((float)(c0 + i) - cx) * S_INVSQRT2);
#pragma unroll
        for (int j = 0; j < 6; ++j)            // 6 independent erfs (record y-window edges)
            ey[j] = fast_erf(((float)(by0 - 2 + j) - cy) * S_INVSQRT2);
        float dyq[5];
#pragma unroll
        for (int j = 0; j < 5; ++j) dyq[j] = ey[j + 1] - ey[j];
        int r0 = by0 - 2 - y0;
#pragma unroll
        for (int i = 0; i < W; ++i) {
            int col = c0 + i;
            if (col >= bx0 - 2 && col <= bx0 + 2) {    // truncation window mask
                float dxq = 0.25f * (ex[i + 1] - ex[i]);
                int cb = i * KSTRIDE + ke;
#pragma unroll
                for (int j = 0; j < 5; ++j) {
                    int rl = r0 + j;
                    if ((unsigned)rl < YB_ROWS)
                        atomicAdd(&acc[rl * (W * KSTRIDE) + cb], dxq * dyq[j]);
                }
            }
        }
        v = vn; kc = kn; idx = nidx;
    }
    __syncthreads();

    // fused quantization reduce: one thread per owned (row, col) bin
    if (tid < YB_ROWS * W) {
        const float4* p = (const float4*)(acc + tid * KSTRIDE);
        float tot2 = 0.f, halves = 0.f;
#pragma unroll
        for (int ck = 0; ck < NCK; ++ck) {
            float q = 0.f;
#pragma unroll
            for (int h2 = 0; h2 < 2; ++h2) {
                float4 d = p[ck * 2 + h2];
                tot2 += d.x + d.y + d.z + d.w;
                q += ceilf(d.x * 0.25f) + ceilf(d.y * 0.25f) +
                     ceilf(d.z * 0.25f) + ceilf(d.w * 0.25f);
            }
            halves += ceilf(0.5f * q);
        }
        float slices = ceilf(0.5f * halves);
        int rl = tid >> 2, cl = tid & 3;
        scale[(c0 + cl) * NBY + y0 + rl] = (tot2 > 0.f) ? (slices / fmaxf(tot2, 1e-12f)) : 0.f;
    }
}

__global__ void ff_gather(const float* __restrict__ pos,
                          const float* __restrict__ nsx,
                          const float* __restrict__ nsy,
                          const int* __restrict__ fi,
                          const float* __restrict__ scale,
                          float* __restrict__ out) {
    int f = blockIdx.x * blockDim.x + threadIdx.x;
    if (f >= NUM_FLOPS) return;
    int i = fi[f];
    float cx = pos[i] + 0.5f * nsx[i];
    float cy = pos[NUM_NODES + i] + 0.5f * nsy[i];
    int bx0 = (int)floorf(cx); bx0 = bx0 < 0 ? 0 : (bx0 > NBX - 1 ? NBX - 1 : bx0);
    int by0 = (int)floorf(cy); by0 = by0 < 0 ? 0 : (by0 > NBY - 1 ? NBY - 1 : by0);
    out[i] = scale[bx0 * NBY + by0];
}

extern "C" void kernel_launch(void* const* d_in, const int* in_sizes, int n_in,
                              void* d_out, int out_size, void* d_ws, size_t ws_size,
                              hipStream_t stream) {
    const float* pos = (const float*)d_in[0];
    const float* nsx = (const float*)d_in[1];
    const float* nsy = (const float*)d_in[2];
    const int*   fi  = (const int*)d_in[3];
    const int*   cs  = (const int*)d_in[4];
    float* out = (float*)d_out;

    float* scale = (float*)d_ws;
    int*   cnt   = (int*)(scale + NBINS);
    Rec12* rec   = (Rec12*)(scale + NBINS + NBUCK);

    hipMemsetAsync(cnt, 0, NBUCK * sizeof(int), stream);

    ff_fill<<<784, 1024, 0, stream>>>(pos, nsx, nsy, fi, cs, cnt, rec, out);
    ff_main<<<dim3(NBX / W, NYB), 512, 0, stream>>>(cnt, rec, scale);
    ff_gather<<<(NUM_FLOPS + 255) / 256, 256, 0, stream>>>(pos, nsx, nsy, fi, scale, out);
}

// Round 2
// 232.665 us; speedup vs baseline: 1.0440x; 1.0440x over previous
//
#include <hip/hip_runtime.h>
#include <math.h>

#define NUM_NODES 2000000
#define NUM_FLOPS 800000
#define NBX 168
#define NBY 480
#define NCK 8
#define NCE 8
#define NBINS (NBX * NBY)          // 80,640
#define YB_ROWS 20                 // y-bucket / tile granularity (was 30)
#define NYB 24                     // y-buckets per column
#define NBUCK (NYB * NBX)          // 4,032 buckets; id = yb*NBX + col (cols contiguous!)
#define CAPB 416                   // expected worst bucket ~312 (edge col+clip) +4sigma ~384
#define W 4                        // columns owned per ff_main block (tile = 20 rows x 4 cols)
#define KSTRIDE 68                 // ke-dim stride (64 + 4 pad) -> 8-way bank spread on reduce
#define S_INVSQRT2 0.7071067811865476f
#define FILL_THREADS (784 * 1024)  // >= NUM_FLOPS

// -------- workspace layout --------
// scale : float [NBINS]               @ float-offset 0          (322.6 KB)
// cnt   : int   [NBUCK]               @ float-offset NBINS      (16.1 KB)
// rec   : Rec12 [NBUCK * CAPB]        (20.13 MB)
// total 20.47 MB (< 20.97 MB proven in prior session)

struct Rec12 { float cx, cy; int keby; };   // keby = (by0 << 6) | ke

// Branch-free erf, Abramowitz-Stegun 7.1.26 (max abs err 1.5e-7).
__device__ __forceinline__ float fast_erf(float x) {
    float ax = fabsf(x);
    float t = __builtin_amdgcn_rcpf(fmaf(0.3275911f, ax, 1.0f));
    float p = t * fmaf(t, fmaf(t, fmaf(t, fmaf(t, 1.061405429f, -1.453152027f),
                                       1.421413741f), -0.284496736f), 0.254829592f);
    float r = fmaf(-p, __expf(-ax * ax), 1.0f);
    return copysignf(r, x);
}

// guaranteed no-return, relaxed, workgroup-scope LDS float add (ds_add_f32)
__device__ __forceinline__ void lds_fadd(float* p, float v) {
    __hip_atomic_fetch_add(p, v, __ATOMIC_RELAXED, __HIP_MEMORY_SCOPE_WORKGROUP);
}

__global__ void __launch_bounds__(1024)
ff_fill(const float* __restrict__ pos,
        const float* __restrict__ nsx,
        const float* __restrict__ nsy,
        const int* __restrict__ fi,
        const int* __restrict__ cs,
        int* __restrict__ cnt,
        Rec12* __restrict__ rec,
        float* __restrict__ out) {
    __shared__ int h[NBUCK];
    __shared__ int base[NBUCK];
    int tid = threadIdx.x;
    int f = blockIdx.x * blockDim.x + tid;

    // fused: zero the output array (replaces a memset dispatch)
    for (int g = f; g < NUM_NODES; g += FILL_THREADS) out[g] = 0.f;

    for (int j = tid; j < NBUCK; j += 1024) h[j] = 0;
    __syncthreads();

    bool valid = (f < NUM_FLOPS);
    int b1 = 0, b2 = -1, r1 = 0, r2 = 0, keby = 0;
    float cx = 0.f, cy = 0.f;
    if (valid) {
        int i = fi[f];
        cx = pos[i] + 0.5f * nsx[i];
        cy = pos[NUM_NODES + i] + 0.5f * nsy[i];
        int bx0 = (int)floorf(cx); bx0 = bx0 < 0 ? 0 : (bx0 > NBX - 1 ? NBX - 1 : bx0);
        int by0 = (int)floorf(cy); by0 = by0 < 0 ? 0 : (by0 > NBY - 1 ? NBY - 1 : by0);
        int2 cc = ((const int2*)cs)[f];
        keby = (by0 << 6) | (cc.x * NCE + cc.y);
        int yb = by0 / YB_ROWS;
        int rlo = by0 - yb * YB_ROWS;
        b1 = yb * NBX + bx0;
        r1 = atomicAdd(&h[b1], 1);
        if (rlo <= 1 && yb > 0)                       b2 = b1 - NBX;   // halo up
        else if (rlo >= YB_ROWS - 2 && yb < NYB - 1)  b2 = b1 + NBX;   // halo down
        if (b2 >= 0) r2 = atomicAdd(&h[b2], 1);
    }
    __syncthreads();
    for (int j = tid; j < NBUCK; j += 1024)
        base[j] = h[j] ? atomicAdd(&cnt[j], h[j]) : 0;   // one global atomic per (block,bucket)
    __syncthreads();
    if (valid) {
        Rec12 v; v.cx = cx; v.cy = cy; v.keby = keby;
        int s1 = base[b1] + r1;
        if (s1 < CAPB) rec[(size_t)b1 * CAPB + s1] = v;
        if (b2 >= 0) {
            int s2 = base[b2] + r2;
            if (s2 < CAPB) rec[(size_t)b2 * CAPB + s2] = v;
        }
    }
}

// Block owns a 20-row x W-column x 64-ke LDS tile. It reads the W+4 contiguous
// buckets whose records can touch its columns; each record is visited by only
// ~2 blocks. One visit serves up to W output columns with W+1 shared x-edge
// erfs and 6 INDEPENDENT y-edge erfs. Grid = 42x24 = 1008 blocks ~= 4/CU
// (the wave cap) in one round -> full occupancy, no tail round.
__global__ void __launch_bounds__(512)
ff_main(const int* __restrict__ cnt,
        const Rec12* __restrict__ rec,
        float* __restrict__ scale) {
    __shared__ __align__(16) float acc[YB_ROWS * W * KSTRIDE];   // 5,440 f = 21,760 B
    int tid = threadIdx.x;
    int c0 = blockIdx.x * W;
    int yb = blockIdx.y;
    int y0 = yb * YB_ROWS;

    for (int j = tid; j < YB_ROWS * W * KSTRIDE; j += 512) acc[j] = 0.f;
    __syncthreads();

    // merged dense iteration over the (<= W+4) contiguous buckets
    int c_lo = c0 - 2 < 0 ? 0 : c0 - 2;
    int c_hi = c0 + W + 1 > NBX - 1 ? NBX - 1 : c0 + W + 1;
    int nb = c_hi - c_lo + 1;                  // 6..8
    int start[9];
    start[0] = 0;
#pragma unroll
    for (int k = 0; k < 8; ++k) {              // fully unrolled -> register-resident
        int n = 0;
        if (k < nb) { n = cnt[yb * NBX + c_lo + k]; n = n < CAPB ? n : CAPB; }
        start[k + 1] = start[k] + n;
    }
    int tot = start[8];
    const Rec12* bb = rec + (size_t)(yb * NBX + c_lo) * CAPB;

    int idx = tid;
    Rec12 v = {}; int kc = 0;
    if (idx < tot) {
        int k = 0, off = idx;
#pragma unroll
        for (int t = 1; t < 8; ++t) { bool g = idx >= start[t]; k = g ? t : k; off = g ? idx - start[t] : off; }
        v = bb[(size_t)k * CAPB + off];
        kc = k;
    }
    while (idx < tot) {
        // ---- prefetch next record (overlaps with compute below) ----
        int nidx = idx + 512;
        Rec12 vn = {}; int kn = 0;
        if (nidx < tot) {
            int k = 0, off = nidx;
#pragma unroll
            for (int t = 1; t < 8; ++t) { bool g = nidx >= start[t]; k = g ? t : k; off = g ? nidx - start[t] : off; }
            vn = bb[(size_t)k * CAPB + off];
            kn = k;
        }
        // ---- process current record ----
        float cx = v.cx, cy = v.cy;
        int ke  = v.keby & 63;
        int by0 = v.keby >> 6;
        int bx0 = c_lo + kc;                   // bucket column == record's bx0 (free!)
        float ex[W + 1], ey[6];
#pragma unroll
        for (int i = 0; i <= W; ++i)           // W+1 independent erfs (owned-column edges)
            ex[i] = fast_erf(((float)(c0 + i) - cx) * S_INVSQRT2);
#pragma unroll
        for (int j = 0; j < 6; ++j)            // 6 independent erfs (record y-window edges)
            ey[j] = fast_erf(((float)(by0 - 2 + j) - cy) * S_INVSQRT2);
        float dyq[5];
#pragma unroll
        for (int j = 0; j < 5; ++j) dyq[j] = ey[j + 1] - ey[j];
        int r0 = by0 - 2 - y0;
#pragma unroll
        for (int i = 0; i < W; ++i) {
            int col = c0 + i;
            if (col >= bx0 - 2 && col <= bx0 + 2) {    // truncation window mask
                float dxq = 0.25f * (ex[i + 1] - ex[i]);
                int cb = i * KSTRIDE + ke;
#pragma unroll
                for (int j = 0; j < 5; ++j) {
                    int rl = r0 + j;
                    if ((unsigned)rl < YB_ROWS)
                        lds_fadd(&acc[rl * (W * KSTRIDE) + cb], dxq * dyq[j]);
                }
            }
        }
        v = vn; kc = kn; idx = nidx;
    }
    __syncthreads();

    // fused quantization reduce: one thread per owned (row, col) bin
    if (tid < YB_ROWS * W) {
        const float4* p = (const float4*)(acc + tid * KSTRIDE);
        float tot2 = 0.f, halves = 0.f;
#pragma unroll
        for (int ck = 0; ck < NCK; ++ck) {
            float q = 0.f;
#pragma unroll
            for (int h2 = 0; h2 < 2; ++h2) {
                float4 d = p[ck * 2 + h2];
                tot2 += d.x + d.y + d.z + d.w;
                q += ceilf(d.x * 0.25f) + ceilf(d.y * 0.25f) +
                     ceilf(d.z * 0.25f) + ceilf(d.w * 0.25f);
            }
            halves += ceilf(0.5f * q);
        }
        float slices = ceilf(0.5f * halves);
        int rl = tid >> 2, cl = tid & 3;
        scale[(c0 + cl) * NBY + y0 + rl] = (tot2 > 0.f) ? (slices / fmaxf(tot2, 1e-12f)) : 0.f;
    }
}

__global__ void ff_gather(const float* __restrict__ pos,
                          const float* __restrict__ nsx,
                          const float* __restrict__ nsy,
                          const int* __restrict__ fi,
                          const float* __restrict__ scale,
                          float* __restrict__ out) {
    int f = blockIdx.x * blockDim.x + threadIdx.x;
    if (f >= NUM_FLOPS) return;
    int i = fi[f];
    float cx = pos[i] + 0.5f * nsx[i];
    float cy = pos[NUM_NODES + i] + 0.5f * nsy[i];
    int bx0 = (int)floorf(cx); bx0 = bx0 < 0 ? 0 : (bx0 > NBX - 1 ? NBX - 1 : bx0);
    int by0 = (int)floorf(cy); by0 = by0 < 0 ? 0 : (by0 > NBY - 1 ? NBY - 1 : by0);
    out[i] = scale[bx0 * NBY + by0];
}

extern "C" void kernel_launch(void* const* d_in, const int* in_sizes, int n_in,
                              void* d_out, int out_size, void* d_ws, size_t ws_size,
                              hipStream_t stream) {
    const float* pos = (const float*)d_in[0];
    const float* nsx = (const float*)d_in[1];
    const float* nsy = (const float*)d_in[2];
    const int*   fi  = (const int*)d_in[3];
    const int*   cs  = (const int*)d_in[4];
    float* out = (float*)d_out;

    float* scale = (float*)d_ws;
    int*   cnt   = (int*)(scale + NBINS);
    Rec12* rec   = (Rec12*)(scale + NBINS + NBUCK);

    hipMemsetAsync(cnt, 0, NBUCK * sizeof(int), stream);

    ff_fill<<<784, 1024, 0, stream>>>(pos, nsx, nsy, fi, cs, cnt, rec, out);
    ff_main<<<dim3(NBX / W, NYB), 512, 0, stream>>>(cnt, rec, scale);
    ff_gather<<<(NUM_FLOPS + 255) / 256, 256, 0, stream>>>(pos, nsx, nsy, fi, scale, out);
}